// Round 11
// baseline (222.586 us; speedup 1.0000x reference)
//
#include <hip/hip_runtime.h>
#include <stdint.h>

typedef unsigned short ushortT;

#define NROWS 131072
#define DIM 64
#define KCODES 1024
#define NSEG 6
#define KTOT (NSEG * DIM)   // 384
#define NKC (KTOT / 32)     // 12 K-chunks of 32
#define MT 128              // rows per block (512 threads, 8 waves)
#define NTC 256             // codes per code-iter (4 code-groups x 64)
#define CI (KCODES / NTC)   // 4 code iters
#define KCSTEP (4 * KCODES * 8)  // ushort elements per kc plane of Bg = 32768
#define ASTEP (4 * MT * 8)       // ushort elements per kc plane of A_lds = 4096

typedef float f32x4 __attribute__((ext_vector_type(4)));
typedef short bf16x8 __attribute__((ext_vector_type(8)));

__device__ __forceinline__ ushortT f2bf(float f) {
  union { float f; uint32_t u; } v; v.f = f;
  return (ushortT)((v.u + 0x7FFFu + ((v.u >> 16) & 1u)) >> 16);  // RNE
}
__device__ __forceinline__ float bf2f(ushortT b) {
  union { float f; uint32_t u; } v; v.u = ((uint32_t)b) << 16;
  return v.f;
}

// Expand codebook: 3-level bf16 split, frag-major layout Bg[(kc*4+q)*1024+code][8],
// segment planes along K: sB = {e0,e1,e2,e0,e1,e0}. Also h2[k]=0.5*||e_k||^2 (fp32).
__global__ __launch_bounds__(256) void vq_prep(const float* __restrict__ emb,
                                               ushortT* __restrict__ Bg,
                                               float* __restrict__ h2) {
  const int code = blockIdx.x * 256 + threadIdx.x;
  float e[DIM];
  float s = 0.f;
#pragma unroll
  for (int d = 0; d < DIM; ++d) {
    e[d] = emb[d * KCODES + code];
    s = fmaf(e[d], e[d], s);
  }
  h2[code] = 0.5f * s;
#pragma unroll
  for (int d = 0; d < DIM; ++d) {
    ushortT p0 = f2bf(e[d]); float r1 = e[d] - bf2f(p0);   // exact (Sterbenz)
    ushortT p1 = f2bf(r1);   float r2 = r1 - bf2f(p1);     // exact
    ushortT p2 = f2bf(r2);
    const ushortT pv[3] = {p0, p1, p2};
    const int sB[6] = {0, 1, 2, 0, 1, 0};
#pragma unroll
    for (int seg = 0; seg < 6; ++seg) {
      int k = seg * DIM + d;
      int kc = k >> 5, q = (k >> 3) & 3, j = k & 7;
      Bg[((size_t)((kc * 4 + q) * KCODES + code)) * 8 + j] = pv[sB[seg]];
    }
  }
}

// Block: 512 threads = 8 waves = 2 row-strips x 4 code-groups; 128 rows x 1024
// codes. MT=128 halves per-CU B traffic vs MT=64 (VMEM floor 55->27 us): each
// CU ran 8 blocks x 768KB of Bg re-reads (L1 can't hold 768KB); now 4 blocks.
// A staged once frag-major in LDS (96KB); B global->VGPR, barrier-free K-loop,
// 4-deep in-place b rotation (R9), unroll 1 pins pressure (R5/R6 spill lesson).
__global__ __launch_bounds__(512, 2) void vq_main(const float* __restrict__ x,
                                                  const ushortT* __restrict__ Bg,
                                                  const float* __restrict__ h2,
                                                  const float* __restrict__ emb,
                                                  float* __restrict__ out) {
  __shared__ ushortT A_lds[NKC * 4 * MT * 8];  // 96 KB  [kc][quad][row(128)][8]
  __shared__ float bvs[4][MT];
  __shared__ int bis[4][MT];
  __shared__ int widx_s[MT];

  const int tid = threadIdx.x;
  const int wave = tid >> 6, lane = tid & 63, quad = lane >> 4, lq = lane & 15;
  const int s = wave & 1;    // row strip: rows s*64 .. s*64+63
  const int cg = wave >> 1;  // code group: codes cg*64 .. cg*64+63 within ci-tile
  const size_t rowbase = (size_t)blockIdx.x * MT;

  // ---- stage A: x rows -> 3 bf16 planes, frag-major. thread: row=tid>>2, 16 d's ----
  {
    const int row = tid >> 2, dg = (tid & 3) << 4;  // 512 thr cover 128 rows
    const float4* xr = (const float4*)(x + (rowbase + row) * DIM + dg);
    float v[16];
#pragma unroll
    for (int i = 0; i < 4; ++i) {
      float4 t = xr[i];
      v[4 * i] = t.x; v[4 * i + 1] = t.y; v[4 * i + 2] = t.z; v[4 * i + 3] = t.w;
    }
    ushortT pl[3][16];
#pragma unroll
    for (int i = 0; i < 16; ++i) {
      ushortT a0 = f2bf(v[i]); float r1 = v[i] - bf2f(a0);
      ushortT a1 = f2bf(r1);   float r2 = r1 - bf2f(a1);
      pl[0][i] = a0; pl[1][i] = a1; pl[2][i] = f2bf(r2);
    }
    const int sA[6] = {0, 0, 0, 1, 1, 2};  // x-plane per segment
    const int q0 = (dg & 31) >> 3;         // 0 or 2
#pragma unroll
    for (int seg = 0; seg < 6; ++seg) {
      int kc = seg * 2 + (dg >> 5);
      *(uint4*)&A_lds[kc * ASTEP + q0 * (MT * 8) + row * 8]       = *(uint4*)&pl[sA[seg]][0];
      *(uint4*)&A_lds[kc * ASTEP + (q0 + 1) * (MT * 8) + row * 8] = *(uint4*)&pl[sA[seg]][8];
    }
  }
  __syncthreads();  // A_lds ready; only block-wide barrier before epilogue

  float bestv[4][4];
  int besti[4][4];
#pragma unroll
  for (int i = 0; i < 4; ++i)
#pragma unroll
    for (int r = 0; r < 4; ++r) { bestv[i][r] = 3.4e38f; besti[i][r] = 0; }

#pragma unroll 1
  for (int ci = 0; ci < CI; ++ci) {
    const int codeBase = ci * NTC;
    f32x4 acc[4][4];
#pragma unroll
    for (int i = 0; i < 4; ++i)
#pragma unroll
      for (int j = 0; j < 4; ++j) acc[i][j] = (f32x4){0.f, 0.f, 0.f, 0.f};

    // lane's B base (kc=0) and A base for this ci
    const ushortT* bp0 =
        Bg + ((size_t)(quad * KCODES + codeBase + cg * 64 + lq)) * 8;
    const ushortT* ab = &A_lds[quad * (MT * 8) + (s * 64 + lq) * 8];

    // 4-deep rotation: b[t] holds kc = g*4 + t
    bf16x8 b[4][4];
#pragma unroll
    for (int t = 0; t < 4; ++t)
#pragma unroll
      for (int j = 0; j < 4; ++j)
        b[t][j] = *(const bf16x8*)(bp0 + (size_t)t * KCSTEP + j * 128);

    const ushortT* bpre = bp0 + 4 * (size_t)KCSTEP;

#pragma unroll 1
    for (int g = 0; g < 3; ++g) {
      const ushortT* pre = (g < 2) ? bpre : bp0;  // last group: harmless self-range reload
#pragma unroll
      for (int t = 0; t < 4; ++t) {
        bf16x8 a[4];
#pragma unroll
        for (int i = 0; i < 4; ++i)
          a[i] = *(const bf16x8*)(ab + t * ASTEP + i * 128);  // row chunk i*16+lq
#pragma unroll
        for (int i = 0; i < 4; ++i)
#pragma unroll
          for (int j = 0; j < 4; ++j)
            acc[i][j] = __builtin_amdgcn_mfma_f32_16x16x32_bf16(a[i], b[t][j], acc[i][j], 0, 0, 0);
        // reload this set from kc+4 (in-place: WAR keeps it after the MFMAs)
#pragma unroll
        for (int j = 0; j < 4; ++j)
          b[t][j] = *(const bf16x8*)(pre + (size_t)t * KCSTEP + j * 128);
      }
      bpre += 4 * (size_t)KCSTEP;
      ab += 4 * ASTEP;
    }

    // epilogue: val = 0.5||e||^2 - f.e ; merge into per-row running best
    float h2v[4];
#pragma unroll
    for (int j = 0; j < 4; ++j) h2v[j] = h2[codeBase + cg * 64 + j * 16 + lq];
#pragma unroll
    for (int i = 0; i < 4; ++i)
#pragma unroll
      for (int j = 0; j < 4; ++j) {
        const int idx = codeBase + cg * 64 + j * 16 + lq;
#pragma unroll
        for (int r = 0; r < 4; ++r) {
          float val = h2v[j] - acc[i][j][r];
          if (val < bestv[i][r]) { bestv[i][r] = val; besti[i][r] = idx; }  // idx ascending in (ci,j): strict < keeps lowest
        }
      }
  }

  // reduce across the 16 lanes sharing a quad (lane bits 0-3), lexicographic (val, idx)
#pragma unroll
  for (int m = 1; m < 16; m <<= 1) {
#pragma unroll
    for (int i = 0; i < 4; ++i)
#pragma unroll
      for (int r = 0; r < 4; ++r) {
        float ov = __shfl_xor(bestv[i][r], m, 64);
        int oi = __shfl_xor(besti[i][r], m, 64);
        if (ov < bestv[i][r] || (ov == bestv[i][r] && oi < besti[i][r])) {
          bestv[i][r] = ov; besti[i][r] = oi;
        }
      }
  }
  if (lq == 0) {
#pragma unroll
    for (int i = 0; i < 4; ++i)
#pragma unroll
      for (int r = 0; r < 4; ++r) {
        int row = s * 64 + i * 16 + quad * 4 + r;  // 0..127
        bvs[cg][row] = bestv[i][r];
        bis[cg][row] = besti[i][r];
      }
  }
  __syncthreads();
  if (tid < MT) {
    float bv = bvs[0][tid]; int bi = bis[0][tid];
#pragma unroll
    for (int c = 1; c < 4; ++c) {
      float ov = bvs[c][tid]; int oi = bis[c][tid];
      if (ov < bv || (ov == bv && oi < bi)) { bv = ov; bi = oi; }
    }
    widx_s[tid] = bi;
  }
  __syncthreads();
  // cooperative gather: thread handles row=tid>>2, 16 d's; emb is L2-resident (256KB)
  {
    const int row = tid >> 2, dg = (tid & 3) << 4;
    const int wi = widx_s[row];
    float4* o = (float4*)(out + (rowbase + row) * DIM + dg);
#pragma unroll
    for (int i = 0; i < 4; ++i) {
      float4 t;
      t.x = emb[(dg + 4 * i + 0) * KCODES + wi];
      t.y = emb[(dg + 4 * i + 1) * KCODES + wi];
      t.z = emb[(dg + 4 * i + 2) * KCODES + wi];
      t.w = emb[(dg + 4 * i + 3) * KCODES + wi];
      o[i] = t;
    }
  }
}

extern "C" void kernel_launch(void* const* d_in, const int* in_sizes, int n_in,
                              void* d_out, int out_size, void* d_ws, size_t ws_size,
                              hipStream_t stream) {
  const float* x = (const float*)d_in[0];
  const float* emb = (const float*)d_in[1];
  float* out = (float*)d_out;

  ushortT* Bg = (ushortT*)d_ws;               // 12*4*1024*8 ushort = 768 KB
  float* h2 = (float*)(Bg + NKC * 4 * KCODES * 8);  // 4 KB

  vq_prep<<<KCODES / 256, 256, 0, stream>>>(emb, Bg, h2);
  vq_main<<<NROWS / MT, 512, 0, stream>>>(x, Bg, h2, emb, out);
}

// Round 12
// 199.855 us; speedup vs baseline: 1.1137x; 1.1137x over previous
//
#include <hip/hip_runtime.h>
#include <stdint.h>

typedef unsigned short ushortT;

#define NROWS 131072
#define DIM 64
#define KCODES 1024
#define NSEG 6
#define KTOT (NSEG * DIM)   // 384
#define NKC (KTOT / 32)     // 12 K-chunks of 32
#define MT 64               // rows per block (256 threads, 4 waves)
#define NTC 256             // codes per code-iter (4 waves x 64)
#define CI (KCODES / NTC)   // 4 code iters
#define KCSTEP (4 * KCODES * 8)  // ushort elements per kc plane of Bg = 32768
#define ASTEP (4 * MT * 8)       // ushort elements per kc plane of A_lds = 2048

typedef float f32x4 __attribute__((ext_vector_type(4)));
typedef short bf16x8 __attribute__((ext_vector_type(8)));

__device__ __forceinline__ ushortT f2bf(float f) {
  union { float f; uint32_t u; } v; v.f = f;
  return (ushortT)((v.u + 0x7FFFu + ((v.u >> 16) & 1u)) >> 16);  // RNE
}
__device__ __forceinline__ float bf2f(ushortT b) {
  union { float f; uint32_t u; } v; v.u = ((uint32_t)b) << 16;
  return v.f;
}

// Expand codebook: 3-level bf16 split, frag-major layout Bg[(kc*4+q)*1024+code][8],
// segment planes along K: sB = {e0,e1,e2,e0,e1,e0}. Also h2[k]=0.5*||e_k||^2 (fp32).
__global__ __launch_bounds__(256) void vq_prep(const float* __restrict__ emb,
                                               ushortT* __restrict__ Bg,
                                               float* __restrict__ h2) {
  const int code = blockIdx.x * 256 + threadIdx.x;
  float e[DIM];
  float s = 0.f;
#pragma unroll
  for (int d = 0; d < DIM; ++d) {
    e[d] = emb[d * KCODES + code];
    s = fmaf(e[d], e[d], s);
  }
  h2[code] = 0.5f * s;
#pragma unroll
  for (int d = 0; d < DIM; ++d) {
    ushortT p0 = f2bf(e[d]); float r1 = e[d] - bf2f(p0);   // exact (Sterbenz)
    ushortT p1 = f2bf(r1);   float r2 = r1 - bf2f(p1);     // exact
    ushortT p2 = f2bf(r2);
    const ushortT pv[3] = {p0, p1, p2};
    const int sB[6] = {0, 1, 2, 0, 1, 0};
#pragma unroll
    for (int seg = 0; seg < 6; ++seg) {
      int k = seg * DIM + d;
      int kc = k >> 5, q = (k >> 3) & 3, j = k & 7;
      Bg[((size_t)((kc * 4 + q) * KCODES + code)) * 8 + j] = pv[sB[seg]];
    }
  }
}

// R10 shape (best: 136us): 256 thr = 4 waves, 64 rows x 1024 codes, A in 48KB
// LDS, B global->VGPR L2-hot, barrier-free K-loop, launch_bounds(256,3).
// NEW (R12): A-fragment register prefetch. R10's per-step critical path was
// ds_read latency (~120-156 cyc) serial with 16 MFMA (~77 cyc) -> duty 39%,
// matching MfmaUtil 33%. Now a(kc+1) ds_reads issue BEFORE kc's MFMAs
// (2-set ping-pong, no copies); b rotation depth 4->2 (R8: depth immaterial)
// keeps total registers unchanged -> no spill at 3 blocks/CU.
__global__ __launch_bounds__(256, 3) void vq_main(const float* __restrict__ x,
                                                  const ushortT* __restrict__ Bg,
                                                  const float* __restrict__ h2,
                                                  const float* __restrict__ emb,
                                                  float* __restrict__ out) {
  __shared__ ushortT A_lds[NKC * ASTEP];  // 48 KB  [kc][quad][row][8]
  __shared__ float bvs[4][MT];
  __shared__ int bis[4][MT];
  __shared__ int widx_s[MT];

  const int tid = threadIdx.x;
  const int wave = tid >> 6, lane = tid & 63, quad = lane >> 4, lq = lane & 15;
  const size_t rowbase = (size_t)blockIdx.x * MT;

  // ---- stage A: x rows -> 3 bf16 planes, frag-major. thread: row=tid>>2, 16 d's ----
  {
    const int row = tid >> 2, dg = (tid & 3) << 4;
    const float4* xr = (const float4*)(x + (rowbase + row) * DIM + dg);
    float v[16];
#pragma unroll
    for (int i = 0; i < 4; ++i) {
      float4 t = xr[i];
      v[4 * i] = t.x; v[4 * i + 1] = t.y; v[4 * i + 2] = t.z; v[4 * i + 3] = t.w;
    }
    ushortT pl[3][16];
#pragma unroll
    for (int i = 0; i < 16; ++i) {
      ushortT a0 = f2bf(v[i]); float r1 = v[i] - bf2f(a0);
      ushortT a1 = f2bf(r1);   float r2 = r1 - bf2f(a1);
      pl[0][i] = a0; pl[1][i] = a1; pl[2][i] = f2bf(r2);
    }
    const int sA[6] = {0, 0, 0, 1, 1, 2};  // x-plane per segment
    const int q0 = (dg & 31) >> 3;         // 0 or 2
#pragma unroll
    for (int seg = 0; seg < 6; ++seg) {
      int kc = seg * 2 + (dg >> 5);
      *(uint4*)&A_lds[kc * ASTEP + q0 * (MT * 8) + row * 8]       = *(uint4*)&pl[sA[seg]][0];
      *(uint4*)&A_lds[kc * ASTEP + (q0 + 1) * (MT * 8) + row * 8] = *(uint4*)&pl[sA[seg]][8];
    }
  }
  __syncthreads();  // A_lds ready; only block-wide barrier before epilogue

  float bestv[4][4];
  int besti[4][4];
#pragma unroll
  for (int i = 0; i < 4; ++i)
#pragma unroll
    for (int r = 0; r < 4; ++r) { bestv[i][r] = 3.4e38f; besti[i][r] = 0; }

#pragma unroll 1
  for (int ci = 0; ci < CI; ++ci) {
    const int codeBase = ci * NTC;
    f32x4 acc[4][4];
#pragma unroll
    for (int i = 0; i < 4; ++i)
#pragma unroll
      for (int j = 0; j < 4; ++j) acc[i][j] = (f32x4){0.f, 0.f, 0.f, 0.f};

    // lane's B base (kc=0) and A base for this ci
    const ushortT* bp0 =
        Bg + ((size_t)(quad * KCODES + codeBase + wave * 64 + lq)) * 8;
    const ushortT* ab = &A_lds[quad * (MT * 8) + lq * 8];

    bf16x8 a[2][4], b[2][4];
#pragma unroll
    for (int j = 0; j < 4; ++j) b[0][j] = *(const bf16x8*)(bp0 + j * 128);
#pragma unroll
    for (int j = 0; j < 4; ++j) b[1][j] = *(const bf16x8*)(bp0 + KCSTEP + j * 128);
#pragma unroll
    for (int i = 0; i < 4; ++i) a[0][i] = *(const bf16x8*)(ab + i * 128);

    const ushortT* bpre = bp0 + 2 * (size_t)KCSTEP;  // b prefetch: kc+2
    const ushortT* ap = ab;                          // a base for kc = 2g

#pragma unroll 1
    for (int g = 0; g < 6; ++g) {
      const ushortT* bq = (g < 5) ? bpre : bp0;  // last group: harmless self-range reload
      // --- t=0 (kc=2g): prefetch a(kc=2g+1) BEFORE the MFMAs ---
#pragma unroll
      for (int i = 0; i < 4; ++i)
        a[1][i] = *(const bf16x8*)(ap + ASTEP + i * 128);
#pragma unroll
      for (int i = 0; i < 4; ++i)
#pragma unroll
        for (int j = 0; j < 4; ++j)
          acc[i][j] = __builtin_amdgcn_mfma_f32_16x16x32_bf16(a[0][i], b[0][j], acc[i][j], 0, 0, 0);
#pragma unroll
      for (int j = 0; j < 4; ++j) b[0][j] = *(const bf16x8*)(bq + j * 128);  // kc=2g+2
      // --- t=1 (kc=2g+1): prefetch a(kc=2g+2) BEFORE the MFMAs ---
      {
        const ushortT* an = (g < 5) ? (ap + 2 * ASTEP) : ab;
#pragma unroll
        for (int i = 0; i < 4; ++i)
          a[0][i] = *(const bf16x8*)(an + i * 128);
      }
#pragma unroll
      for (int i = 0; i < 4; ++i)
#pragma unroll
        for (int j = 0; j < 4; ++j)
          acc[i][j] = __builtin_amdgcn_mfma_f32_16x16x32_bf16(a[1][i], b[1][j], acc[i][j], 0, 0, 0);
#pragma unroll
      for (int j = 0; j < 4; ++j) b[1][j] = *(const bf16x8*)(bq + KCSTEP + j * 128);  // kc=2g+3
      bpre += 2 * (size_t)KCSTEP;
      ap += 2 * ASTEP;
    }

    // epilogue: val = 0.5||e||^2 - f.e ; merge into per-row running best
    float h2v[4];
#pragma unroll
    for (int j = 0; j < 4; ++j) h2v[j] = h2[codeBase + wave * 64 + j * 16 + lq];
#pragma unroll
    for (int i = 0; i < 4; ++i)
#pragma unroll
      for (int j = 0; j < 4; ++j) {
        const int idx = codeBase + wave * 64 + j * 16 + lq;
#pragma unroll
        for (int r = 0; r < 4; ++r) {
          float val = h2v[j] - acc[i][j][r];
          if (val < bestv[i][r]) { bestv[i][r] = val; besti[i][r] = idx; }  // idx ascending in (ci,j): strict < keeps lowest
        }
      }
  }

  // reduce across the 16 lanes sharing a quad (lane bits 0-3), lexicographic (val, idx)
#pragma unroll
  for (int m = 1; m < 16; m <<= 1) {
#pragma unroll
    for (int i = 0; i < 4; ++i)
#pragma unroll
      for (int r = 0; r < 4; ++r) {
        float ov = __shfl_xor(bestv[i][r], m, 64);
        int oi = __shfl_xor(besti[i][r], m, 64);
        if (ov < bestv[i][r] || (ov == bestv[i][r] && oi < besti[i][r])) {
          bestv[i][r] = ov; besti[i][r] = oi;
        }
      }
  }
  if (lq == 0) {
#pragma unroll
    for (int i = 0; i < 4; ++i)
#pragma unroll
      for (int r = 0; r < 4; ++r) {
        int row = i * 16 + quad * 4 + r;
        bvs[wave][row] = bestv[i][r];
        bis[wave][row] = besti[i][r];
      }
  }
  __syncthreads();
  if (tid < MT) {
    float bv = bvs[0][tid]; int bi = bis[0][tid];
#pragma unroll
    for (int w = 1; w < 4; ++w) {
      float ov = bvs[w][tid]; int oi = bis[w][tid];
      if (ov < bv || (ov == bv && oi < bi)) { bv = ov; bi = oi; }
    }
    widx_s[tid] = bi;
  }
  __syncthreads();
  // cooperative gather: thread handles row=tid>>2, 16 d's; emb is L2-resident (256KB)
  {
    const int row = tid >> 2, dg = (tid & 3) << 4;
    const int wi = widx_s[row];
    float4* o = (float4*)(out + (rowbase + row) * DIM + dg);
#pragma unroll
    for (int i = 0; i < 4; ++i) {
      float4 t;
      t.x = emb[(dg + 4 * i + 0) * KCODES + wi];
      t.y = emb[(dg + 4 * i + 1) * KCODES + wi];
      t.z = emb[(dg + 4 * i + 2) * KCODES + wi];
      t.w = emb[(dg + 4 * i + 3) * KCODES + wi];
      o[i] = t;
    }
  }
}

extern "C" void kernel_launch(void* const* d_in, const int* in_sizes, int n_in,
                              void* d_out, int out_size, void* d_ws, size_t ws_size,
                              hipStream_t stream) {
  const float* x = (const float*)d_in[0];
  const float* emb = (const float*)d_in[1];
  float* out = (float*)d_out;

  ushortT* Bg = (ushortT*)d_ws;               // 12*4*1024*8 ushort = 768 KB
  float* h2 = (float*)(Bg + NKC * 4 * KCODES * 8);  // 4 KB

  vq_prep<<<KCODES / 256, 256, 0, stream>>>(emb, Bg, h2);
  vq_main<<<NROWS / MT, 256, 0, stream>>>(x, Bg, h2, emb, out);
}

// Round 13
// 188.484 us; speedup vs baseline: 1.1809x; 1.0603x over previous
//
#include <hip/hip_runtime.h>
#include <stdint.h>

typedef unsigned short ushortT;

#define NROWS 131072
#define DIM 64
#define KCODES 1024
#define NSEG 5              // dropped x1*e1 segment: contributes ~4e-6 ~ fp32 ULP noise
#define KTOT (NSEG * DIM)   // 320
#define NKC (KTOT / 32)     // 10 K-chunks of 32
#define MT 64               // rows per block (256 threads, 4 waves)
#define NTC 256             // codes per code-iter (4 waves x 64)
#define CI (KCODES / NTC)   // 4 code iters
#define KCSTEP (4 * KCODES * 8)  // ushort elements per kc plane of Bg = 32768
#define ASTEP (4 * MT * 8)       // ushort elements per kc plane of A_lds = 2048

typedef float f32x4 __attribute__((ext_vector_type(4)));
typedef short bf16x8 __attribute__((ext_vector_type(8)));

__device__ __forceinline__ ushortT f2bf(float f) {
  union { float f; uint32_t u; } v; v.f = f;
  return (ushortT)((v.u + 0x7FFFu + ((v.u >> 16) & 1u)) >> 16);  // RNE
}
__device__ __forceinline__ float bf2f(ushortT b) {
  union { float f; uint32_t u; } v; v.u = ((uint32_t)b) << 16;
  return v.f;
}

// Expand codebook: bf16 split, 5 segments (x-plane, e-plane) =
// (0,0),(0,1),(0,2),(1,0),(2,0) — x1e1 dropped (error ~4e-6 ≈ fp32 ulp).
// Frag-major Bg[(kc*4+q)*1024+code][8]; h2[k]=0.5*||e_k||^2 (fp32).
__global__ __launch_bounds__(256) void vq_prep(const float* __restrict__ emb,
                                               ushortT* __restrict__ Bg,
                                               float* __restrict__ h2) {
  const int code = blockIdx.x * 256 + threadIdx.x;
  float e[DIM];
  float s = 0.f;
#pragma unroll
  for (int d = 0; d < DIM; ++d) {
    e[d] = emb[d * KCODES + code];
    s = fmaf(e[d], e[d], s);
  }
  h2[code] = 0.5f * s;
#pragma unroll
  for (int d = 0; d < DIM; ++d) {
    ushortT p0 = f2bf(e[d]); float r1 = e[d] - bf2f(p0);   // exact (Sterbenz)
    ushortT p1 = f2bf(r1);   float r2 = r1 - bf2f(p1);     // exact
    ushortT p2 = f2bf(r2);
    const ushortT pv[3] = {p0, p1, p2};
    const int sB[NSEG] = {0, 1, 2, 0, 0};
#pragma unroll
    for (int seg = 0; seg < NSEG; ++seg) {
      int k = seg * DIM + d;
      int kc = k >> 5, q = (k >> 3) & 3, j = k & 7;
      Bg[((size_t)((kc * 4 + q) * KCODES + code)) * 8 + j] = pv[sB[seg]];
    }
  }
}

// R12 structure (best: 134us @ K=384): 256 thr = 4 waves, 64 rows x 1024 codes,
// A in LDS (40KB @ K=320), B global->VGPR L2-hot, barrier-free K-loop,
// a-prefetch ping-pong, b 2-deep ping-pong, launch_bounds(256,3).
// At the ~36%-of-dense HIP-source plateau (m97-class); this round cuts the
// WORK through the plateau: K 384->320 (x1e1 segment dropped).
__global__ __launch_bounds__(256, 3) void vq_main(const float* __restrict__ x,
                                                  const ushortT* __restrict__ Bg,
                                                  const float* __restrict__ h2,
                                                  const float* __restrict__ emb,
                                                  float* __restrict__ out) {
  __shared__ ushortT A_lds[NKC * ASTEP];  // 40 KB  [kc][quad][row][8]
  __shared__ float bvs[4][MT];
  __shared__ int bis[4][MT];
  __shared__ int widx_s[MT];

  const int tid = threadIdx.x;
  const int wave = tid >> 6, lane = tid & 63, quad = lane >> 4, lq = lane & 15;
  const size_t rowbase = (size_t)blockIdx.x * MT;

  // ---- stage A: x rows -> bf16 planes, frag-major. thread: row=tid>>2, 16 d's ----
  {
    const int row = tid >> 2, dg = (tid & 3) << 4;
    const float4* xr = (const float4*)(x + (rowbase + row) * DIM + dg);
    float v[16];
#pragma unroll
    for (int i = 0; i < 4; ++i) {
      float4 t = xr[i];
      v[4 * i] = t.x; v[4 * i + 1] = t.y; v[4 * i + 2] = t.z; v[4 * i + 3] = t.w;
    }
    ushortT pl[3][16];
#pragma unroll
    for (int i = 0; i < 16; ++i) {
      ushortT a0 = f2bf(v[i]); float r1 = v[i] - bf2f(a0);
      ushortT a1 = f2bf(r1);   float r2 = r1 - bf2f(a1);
      pl[0][i] = a0; pl[1][i] = a1; pl[2][i] = f2bf(r2);
    }
    const int sA[NSEG] = {0, 0, 0, 1, 2};  // x-plane per segment
    const int q0 = (dg & 31) >> 3;         // 0 or 2
#pragma unroll
    for (int seg = 0; seg < NSEG; ++seg) {
      int kc = seg * 2 + (dg >> 5);
      *(uint4*)&A_lds[kc * ASTEP + q0 * (MT * 8) + row * 8]       = *(uint4*)&pl[sA[seg]][0];
      *(uint4*)&A_lds[kc * ASTEP + (q0 + 1) * (MT * 8) + row * 8] = *(uint4*)&pl[sA[seg]][8];
    }
  }
  __syncthreads();  // A_lds ready; only block-wide barrier before epilogue

  float bestv[4][4];
  int besti[4][4];
#pragma unroll
  for (int i = 0; i < 4; ++i)
#pragma unroll
    for (int r = 0; r < 4; ++r) { bestv[i][r] = 3.4e38f; besti[i][r] = 0; }

#pragma unroll 1
  for (int ci = 0; ci < CI; ++ci) {
    const int codeBase = ci * NTC;
    f32x4 acc[4][4];
#pragma unroll
    for (int i = 0; i < 4; ++i)
#pragma unroll
      for (int j = 0; j < 4; ++j) acc[i][j] = (f32x4){0.f, 0.f, 0.f, 0.f};

    // lane's B base (kc=0) and A base for this ci
    const ushortT* bp0 =
        Bg + ((size_t)(quad * KCODES + codeBase + wave * 64 + lq)) * 8;
    const ushortT* ab = &A_lds[quad * (MT * 8) + lq * 8];

    bf16x8 a[2][4], b[2][4];
#pragma unroll
    for (int j = 0; j < 4; ++j) b[0][j] = *(const bf16x8*)(bp0 + j * 128);
#pragma unroll
    for (int j = 0; j < 4; ++j) b[1][j] = *(const bf16x8*)(bp0 + KCSTEP + j * 128);
#pragma unroll
    for (int i = 0; i < 4; ++i) a[0][i] = *(const bf16x8*)(ab + i * 128);

    const ushortT* bpre = bp0 + 2 * (size_t)KCSTEP;  // b prefetch: kc+2
    const ushortT* ap = ab;                          // a base for kc = 2g

#pragma unroll 1
    for (int g = 0; g < NKC / 2; ++g) {
      const ushortT* bq = (g < NKC / 2 - 1) ? bpre : bp0;  // last: harmless self-range reload
      // --- t=0 (kc=2g): prefetch a(kc=2g+1) BEFORE the MFMAs ---
#pragma unroll
      for (int i = 0; i < 4; ++i)
        a[1][i] = *(const bf16x8*)(ap + ASTEP + i * 128);
#pragma unroll
      for (int i = 0; i < 4; ++i)
#pragma unroll
        for (int j = 0; j < 4; ++j)
          acc[i][j] = __builtin_amdgcn_mfma_f32_16x16x32_bf16(a[0][i], b[0][j], acc[i][j], 0, 0, 0);
#pragma unroll
      for (int j = 0; j < 4; ++j) b[0][j] = *(const bf16x8*)(bq + j * 128);  // kc=2g+2
      // --- t=1 (kc=2g+1): prefetch a(kc=2g+2) BEFORE the MFMAs ---
      {
        const ushortT* an = (g < NKC / 2 - 1) ? (ap + 2 * ASTEP) : ab;
#pragma unroll
        for (int i = 0; i < 4; ++i)
          a[0][i] = *(const bf16x8*)(an + i * 128);
      }
#pragma unroll
      for (int i = 0; i < 4; ++i)
#pragma unroll
        for (int j = 0; j < 4; ++j)
          acc[i][j] = __builtin_amdgcn_mfma_f32_16x16x32_bf16(a[1][i], b[1][j], acc[i][j], 0, 0, 0);
#pragma unroll
      for (int j = 0; j < 4; ++j) b[1][j] = *(const bf16x8*)(bq + KCSTEP + j * 128);  // kc=2g+3
      bpre += 2 * (size_t)KCSTEP;
      ap += 2 * ASTEP;
    }

    // epilogue: val = 0.5||e||^2 - f.e ; merge into per-row running best
    float h2v[4];
#pragma unroll
    for (int j = 0; j < 4; ++j) h2v[j] = h2[codeBase + wave * 64 + j * 16 + lq];
#pragma unroll
    for (int i = 0; i < 4; ++i)
#pragma unroll
      for (int j = 0; j < 4; ++j) {
        const int idx = codeBase + wave * 64 + j * 16 + lq;
#pragma unroll
        for (int r = 0; r < 4; ++r) {
          float val = h2v[j] - acc[i][j][r];
          if (val < bestv[i][r]) { bestv[i][r] = val; besti[i][r] = idx; }  // idx ascending in (ci,j): strict < keeps lowest
        }
      }
  }

  // reduce across the 16 lanes sharing a quad (lane bits 0-3), lexicographic (val, idx)
#pragma unroll
  for (int m = 1; m < 16; m <<= 1) {
#pragma unroll
    for (int i = 0; i < 4; ++i)
#pragma unroll
      for (int r = 0; r < 4; ++r) {
        float ov = __shfl_xor(bestv[i][r], m, 64);
        int oi = __shfl_xor(besti[i][r], m, 64);
        if (ov < bestv[i][r] || (ov == bestv[i][r] && oi < besti[i][r])) {
          bestv[i][r] = ov; besti[i][r] = oi;
        }
      }
  }
  if (lq == 0) {
#pragma unroll
    for (int i = 0; i < 4; ++i)
#pragma unroll
      for (int r = 0; r < 4; ++r) {
        int row = i * 16 + quad * 4 + r;
        bvs[wave][row] = bestv[i][r];
        bis[wave][row] = besti[i][r];
      }
  }
  __syncthreads();
  if (tid < MT) {
    float bv = bvs[0][tid]; int bi = bis[0][tid];
#pragma unroll
    for (int w = 1; w < 4; ++w) {
      float ov = bvs[w][tid]; int oi = bis[w][tid];
      if (ov < bv || (ov == bv && oi < bi)) { bv = ov; bi = oi; }
    }
    widx_s[tid] = bi;
  }
  __syncthreads();
  // cooperative gather: thread handles row=tid>>2, 16 d's; emb is L2-resident (256KB)
  {
    const int row = tid >> 2, dg = (tid & 3) << 4;
    const int wi = widx_s[row];
    float4* o = (float4*)(out + (rowbase + row) * DIM + dg);
#pragma unroll
    for (int i = 0; i < 4; ++i) {
      float4 t;
      t.x = emb[(dg + 4 * i + 0) * KCODES + wi];
      t.y = emb[(dg + 4 * i + 1) * KCODES + wi];
      t.z = emb[(dg + 4 * i + 2) * KCODES + wi];
      t.w = emb[(dg + 4 * i + 3) * KCODES + wi];
      o[i] = t;
    }
  }
}

extern "C" void kernel_launch(void* const* d_in, const int* in_sizes, int n_in,
                              void* d_out, int out_size, void* d_ws, size_t ws_size,
                              hipStream_t stream) {
  const float* x = (const float*)d_in[0];
  const float* emb = (const float*)d_in[1];
  float* out = (float*)d_out;

  ushortT* Bg = (ushortT*)d_ws;               // 10*4*1024*8 ushort = 640 KB
  float* h2 = (float*)(Bg + NKC * 4 * KCODES * 8);  // 4 KB

  vq_prep<<<KCODES / 256, 256, 0, stream>>>(emb, Bg, h2);
  vq_main<<<NROWS / MT, 256, 0, stream>>>(x, Bg, h2, emb, out);
}

// Round 15
// 188.399 us; speedup vs baseline: 1.1815x; 1.0005x over previous
//
#include <hip/hip_runtime.h>
#include <stdint.h>

typedef unsigned short ushortT;

#define NROWS 131072
#define DIM 64
#define KCODES 1024
#define NSEG 5              // (x0e0,x0e1,x0e2,x1e0,x2e0): x1e1 dropped (~4e-6 ≈ fp32 ulp).
                            // K=192 (3 seg) FLIPS an argmin (R14: absmax 0.966) — boundary measured.
#define KTOT (NSEG * DIM)   // 320
#define NKC (KTOT / 32)     // 10 K-chunks of 32
#define MT 64               // rows per block (256 threads, 4 waves)
#define NTC 256             // codes per code-iter (4 waves x 64)
#define CI (KCODES / NTC)   // 4 code iters
#define KCSTEP (4 * KCODES * 8)  // ushort elements per kc plane of Bg = 32768
#define ASTEP (4 * MT * 8)       // ushort elements per kc plane of A_lds = 2048

typedef float f32x4 __attribute__((ext_vector_type(4)));
typedef short bf16x8 __attribute__((ext_vector_type(8)));

__device__ __forceinline__ ushortT f2bf(float f) {
  union { float f; uint32_t u; } v; v.f = f;
  return (ushortT)((v.u + 0x7FFFu + ((v.u >> 16) & 1u)) >> 16);  // RNE
}
__device__ __forceinline__ float bf2f(ushortT b) {
  union { float f; uint32_t u; } v; v.u = ((uint32_t)b) << 16;
  return v.f;
}

// Expand codebook: bf16 split, 5 segments (x-plane, e-plane) =
// (0,0),(0,1),(0,2),(1,0),(2,0). Frag-major Bg[(kc*4+q)*1024+code][8];
// h2[k]=0.5*||e_k||^2 (fp32, exact).
__global__ __launch_bounds__(256) void vq_prep(const float* __restrict__ emb,
                                               ushortT* __restrict__ Bg,
                                               float* __restrict__ h2) {
  const int code = blockIdx.x * 256 + threadIdx.x;
  float e[DIM];
  float s = 0.f;
#pragma unroll
  for (int d = 0; d < DIM; ++d) {
    e[d] = emb[d * KCODES + code];
    s = fmaf(e[d], e[d], s);
  }
  h2[code] = 0.5f * s;
#pragma unroll
  for (int d = 0; d < DIM; ++d) {
    ushortT p0 = f2bf(e[d]); float r1 = e[d] - bf2f(p0);   // exact (Sterbenz)
    ushortT p1 = f2bf(r1);   float r2 = r1 - bf2f(p1);     // exact
    ushortT p2 = f2bf(r2);
    const ushortT pv[3] = {p0, p1, p2};
    const int sB[NSEG] = {0, 1, 2, 0, 0};
#pragma unroll
    for (int seg = 0; seg < NSEG; ++seg) {
      int k = seg * DIM + d;
      int kc = k >> 5, q = (k >> 3) & 3, j = k & 7;
      Bg[((size_t)((kc * 4 + q) * KCODES + code)) * 8 + j] = pv[sB[seg]];
    }
  }
}

// R13 verified config (122us, absmax 1.953125e-3): 256 thr = 4 waves, 64 rows x
// 1024 codes, A frag-major in LDS (40KB @ K=320), B global->VGPR L2-hot,
// barrier-free K-loop, a-prefetch ping-pong + b 2-deep ping-pong,
// launch_bounds(256,3), unroll 1 pins register pressure (R5/R6 spill lesson).
__global__ __launch_bounds__(256, 3) void vq_main(const float* __restrict__ x,
                                                  const ushortT* __restrict__ Bg,
                                                  const float* __restrict__ h2,
                                                  const float* __restrict__ emb,
                                                  float* __restrict__ out) {
  __shared__ ushortT A_lds[NKC * ASTEP];  // 40 KB  [kc][quad][row][8]
  __shared__ float bvs[4][MT];
  __shared__ int bis[4][MT];
  __shared__ int widx_s[MT];

  const int tid = threadIdx.x;
  const int wave = tid >> 6, lane = tid & 63, quad = lane >> 4, lq = lane & 15;
  const size_t rowbase = (size_t)blockIdx.x * MT;

  // ---- stage A: x rows -> bf16 planes, frag-major. thread: row=tid>>2, 16 d's ----
  {
    const int row = tid >> 2, dg = (tid & 3) << 4;
    const float4* xr = (const float4*)(x + (rowbase + row) * DIM + dg);
    float v[16];
#pragma unroll
    for (int i = 0; i < 4; ++i) {
      float4 t = xr[i];
      v[4 * i] = t.x; v[4 * i + 1] = t.y; v[4 * i + 2] = t.z; v[4 * i + 3] = t.w;
    }
    ushortT pl[3][16];
#pragma unroll
    for (int i = 0; i < 16; ++i) {
      ushortT a0 = f2bf(v[i]); float r1 = v[i] - bf2f(a0);
      ushortT a1 = f2bf(r1);   float r2 = r1 - bf2f(a1);
      pl[0][i] = a0; pl[1][i] = a1; pl[2][i] = f2bf(r2);
    }
    const int sA[NSEG] = {0, 0, 0, 1, 2};  // x-plane per segment
    const int q0 = (dg & 31) >> 3;         // 0 or 2
#pragma unroll
    for (int seg = 0; seg < NSEG; ++seg) {
      int kc = seg * 2 + (dg >> 5);
      *(uint4*)&A_lds[kc * ASTEP + q0 * (MT * 8) + row * 8]       = *(uint4*)&pl[sA[seg]][0];
      *(uint4*)&A_lds[kc * ASTEP + (q0 + 1) * (MT * 8) + row * 8] = *(uint4*)&pl[sA[seg]][8];
    }
  }
  __syncthreads();  // A_lds ready; only block-wide barrier before epilogue

  float bestv[4][4];
  int besti[4][4];
#pragma unroll
  for (int i = 0; i < 4; ++i)
#pragma unroll
    for (int r = 0; r < 4; ++r) { bestv[i][r] = 3.4e38f; besti[i][r] = 0; }

#pragma unroll 1
  for (int ci = 0; ci < CI; ++ci) {
    const int codeBase = ci * NTC;
    f32x4 acc[4][4];
#pragma unroll
    for (int i = 0; i < 4; ++i)
#pragma unroll
      for (int j = 0; j < 4; ++j) acc[i][j] = (f32x4){0.f, 0.f, 0.f, 0.f};

    // lane's B base (kc=0) and A base for this ci
    const ushortT* bp0 =
        Bg + ((size_t)(quad * KCODES + codeBase + wave * 64 + lq)) * 8;
    const ushortT* ab = &A_lds[quad * (MT * 8) + lq * 8];

    bf16x8 a[2][4], b[2][4];
#pragma unroll
    for (int j = 0; j < 4; ++j) b[0][j] = *(const bf16x8*)(bp0 + j * 128);
#pragma unroll
    for (int j = 0; j < 4; ++j) b[1][j] = *(const bf16x8*)(bp0 + KCSTEP + j * 128);
#pragma unroll
    for (int i = 0; i < 4; ++i) a[0][i] = *(const bf16x8*)(ab + i * 128);

    const ushortT* bpre = bp0 + 2 * (size_t)KCSTEP;  // b prefetch: kc+2
    const ushortT* ap = ab;                          // a base for kc = 2g

#pragma unroll 1
    for (int g = 0; g < NKC / 2; ++g) {
      const ushortT* bq = (g < NKC / 2 - 1) ? bpre : bp0;  // last: harmless self-range reload
      // --- t=0 (kc=2g): prefetch a(kc=2g+1) BEFORE the MFMAs ---
#pragma unroll
      for (int i = 0; i < 4; ++i)
        a[1][i] = *(const bf16x8*)(ap + ASTEP + i * 128);
#pragma unroll
      for (int i = 0; i < 4; ++i)
#pragma unroll
        for (int j = 0; j < 4; ++j)
          acc[i][j] = __builtin_amdgcn_mfma_f32_16x16x32_bf16(a[0][i], b[0][j], acc[i][j], 0, 0, 0);
#pragma unroll
      for (int j = 0; j < 4; ++j) b[0][j] = *(const bf16x8*)(bq + j * 128);  // kc=2g+2
      // --- t=1 (kc=2g+1): prefetch a(kc=2g+2) BEFORE the MFMAs ---
      {
        const ushortT* an = (g < NKC / 2 - 1) ? (ap + 2 * ASTEP) : ab;
#pragma unroll
        for (int i = 0; i < 4; ++i)
          a[0][i] = *(const bf16x8*)(an + i * 128);
      }
#pragma unroll
      for (int i = 0; i < 4; ++i)
#pragma unroll
        for (int j = 0; j < 4; ++j)
          acc[i][j] = __builtin_amdgcn_mfma_f32_16x16x32_bf16(a[1][i], b[1][j], acc[i][j], 0, 0, 0);
#pragma unroll
      for (int j = 0; j < 4; ++j) b[1][j] = *(const bf16x8*)(bq + KCSTEP + j * 128);  // kc=2g+3
      bpre += 2 * (size_t)KCSTEP;
      ap += 2 * ASTEP;
    }

    // epilogue: val = 0.5||e||^2 - f.e ; merge into per-row running best
    float h2v[4];
#pragma unroll
    for (int j = 0; j < 4; ++j) h2v[j] = h2[codeBase + wave * 64 + j * 16 + lq];
#pragma unroll
    for (int i = 0; i < 4; ++i)
#pragma unroll
      for (int j = 0; j < 4; ++j) {
        const int idx = codeBase + wave * 64 + j * 16 + lq;
#pragma unroll
        for (int r = 0; r < 4; ++r) {
          float val = h2v[j] - acc[i][j][r];
          if (val < bestv[i][r]) { bestv[i][r] = val; besti[i][r] = idx; }  // idx ascending in (ci,j): strict < keeps lowest
        }
      }
  }

  // reduce across the 16 lanes sharing a quad (lane bits 0-3), lexicographic (val, idx)
#pragma unroll
  for (int m = 1; m < 16; m <<= 1) {
#pragma unroll
    for (int i = 0; i < 4; ++i)
#pragma unroll
      for (int r = 0; r < 4; ++r) {
        float ov = __shfl_xor(bestv[i][r], m, 64);
        int oi = __shfl_xor(besti[i][r], m, 64);
        if (ov < bestv[i][r] || (ov == bestv[i][r] && oi < besti[i][r])) {
          bestv[i][r] = ov; besti[i][r] = oi;
        }
      }
  }
  if (lq == 0) {
#pragma unroll
    for (int i = 0; i < 4; ++i)
#pragma unroll
      for (int r = 0; r < 4; ++r) {
        int row = i * 16 + quad * 4 + r;
        bvs[wave][row] = bestv[i][r];
        bis[wave][row] = besti[i][r];
      }
  }
  __syncthreads();
  if (tid < MT) {
    float bv = bvs[0][tid]; int bi = bis[0][tid];
#pragma unroll
    for (int w = 1; w < 4; ++w) {
      float ov = bvs[w][tid]; int oi = bis[w][tid];
      if (ov < bv || (ov == bv && oi < bi)) { bv = ov; bi = oi; }
    }
    widx_s[tid] = bi;
  }
  __syncthreads();
  // cooperative gather: thread handles row=tid>>2, 16 d's; emb is L2-resident (256KB)
  {
    const int row = tid >> 2, dg = (tid & 3) << 4;
    const int wi = widx_s[row];
    float4* o = (float4*)(out + (rowbase + row) * DIM + dg);
#pragma unroll
    for (int i = 0; i < 4; ++i) {
      float4 t;
      t.x = emb[(dg + 4 * i + 0) * KCODES + wi];
      t.y = emb[(dg + 4 * i + 1) * KCODES + wi];
      t.z = emb[(dg + 4 * i + 2) * KCODES + wi];
      t.w = emb[(dg + 4 * i + 3) * KCODES + wi];
      o[i] = t;
    }
  }
}

extern "C" void kernel_launch(void* const* d_in, const int* in_sizes, int n_in,
                              void* d_out, int out_size, void* d_ws, size_t ws_size,
                              hipStream_t stream) {
  const float* x = (const float*)d_in[0];
  const float* emb = (const float*)d_in[1];
  float* out = (float*)d_out;

  ushortT* Bg = (ushortT*)d_ws;               // 10*4*1024*8 ushort = 640 KB
  float* h2 = (float*)(Bg + NKC * 4 * KCODES * 8);  // 4 KB

  vq_prep<<<KCODES / 256, 256, 0, stream>>>(emb, Bg, h2);
  vq_main<<<NROWS / MT, 256, 0, stream>>>(x, Bg, h2, emb, out);
}